// Round 3
// baseline (1194.010 us; speedup 1.0000x reference)
//
#include <hip/hip_runtime.h>
#include <math.h>

// Problem constants (from reference)
#define B_  8
#define W_  512
#define U_  12
#define H_  8
#define D_  192
#define K_  24
#define F_  13
#define CH_ 1536
#define UK_ (U_ * K_)   // 288 outputs per (b,w,h)
#define UF_ (U_ * F_)   // 156 bd terms per (b,w,h)

// ---------------------------------------------------------------------------
// Kernel 1: proj[f][o] = sum_c sin_emb[f][c] * pos_w[o][c]
//   sin_emb[f][c] = c<768 ? sin(pos_f * its(c)) : cos(pos_f * its(c-768))
//   its(t) = exp(-t * log(10000)/767), pos_f = 12 - f
// Grid: 13 f * 6 chunks of 256 outputs = 78 blocks, 256 threads.
// pos_w is 9.4 MB -> L2/L3 resident across the 13 re-reads.
// ---------------------------------------------------------------------------
__global__ __launch_bounds__(256) void proj_kernel(const float* __restrict__ pos_w,
                                                   float* __restrict__ proj) {
    __shared__ float emb[CH_];
    const int f     = blockIdx.x / 6;
    const int chunk = blockIdx.x % 6;
    const float pos = (float)(12 - f);
    const float log_inc = 9.210340371976184f / 767.0f;  // log(10000)/max(num_ts-1,1)

    for (int c = threadIdx.x; c < CH_; c += 256) {
        const int t   = (c < 768) ? c : (c - 768);
        const float its = expf(-log_inc * (float)t);
        const float a   = pos * its;
        emb[c] = (c < 768) ? sinf(a) : cosf(a);
    }
    __syncthreads();

    const int o = chunk * 256 + threadIdx.x;
    const float4* pw4 = reinterpret_cast<const float4*>(pos_w) + (size_t)o * (CH_ / 4);
    const float4* e4  = reinterpret_cast<const float4*>(emb);
    float acc = 0.f;
#pragma unroll 4
    for (int i = 0; i < CH_ / 4; ++i) {
        const float4 p = pw4[i];
        const float4 e = e4[i];
        acc += p.x * e.x + p.y * e.y + p.z * e.z + p.w * e.w;
    }
    proj[f * CH_ + o] = acc;   // proj laid out [F][H*D], matches reshape(f,h,d)
}

// ---------------------------------------------------------------------------
// Kernel 2: per (b,w,h) block:
//   term_ac[u][c] = dot(Q[u], K[c]) over d=192
//   term_bd[u][f] = dot(Q[u], proj_h[f])
//   out[u][c]     = term_ac[u][c] + (f'<13 ? term_bd[u'][f'] : 0),
//                   j = u*24+c, u' = j/25, f' = j%25   (rel-shift)
// LDS: 49 rows (12 Q + 24 K + 13 proj) x 48 float4, pitch 49 float4
//      -> consecutive rows offset by 4 banks (196 % 32 == 4), only u/u+8
//         alias 2-way which is free. 40.2 KB total -> 4 blocks/CU.
// ---------------------------------------------------------------------------
__global__ __launch_bounds__(256) void main_kernel(const float* __restrict__ qg,
                                                   const float* __restrict__ kg,
                                                   const float* __restrict__ pj,
                                                   float* __restrict__ out) {
    __shared__ float4 lds4[49 * 49];   // 38416 B
    __shared__ float  bd_s[UF_];       // 624 B
    __shared__ float  out_s[UK_];      // 1152 B

    const int tid = threadIdx.x;
    const int blk = blockIdx.x;
    const int h   = blk & 7;     // H = 8
    const int bw  = blk >> 3;    // b*W + w

    // All three sources have identical row stride: 1536 floats.
    const float* gq = qg + (size_t)bw * (U_ * H_ * D_) + h * D_;  // rows u
    const float* gk = kg + (size_t)bw * (K_ * H_ * D_) + h * D_;  // rows c
    const float* gp = pj + h * D_;                                // rows f

    // Stage 49 rows x 48 float4 (rows are contiguous 768 B in global).
    for (int i = tid; i < 49 * 48; i += 256) {
        const int r   = i / 48;
        const int col = i - r * 48;
        const float* src = (r < 12) ? (gq + r * 1536)
                         : (r < 36) ? (gk + (r - 12) * 1536)
                                    : (gp + (r - 36) * 1536);
        lds4[r * 49 + col] = reinterpret_cast<const float4*>(src)[col];
    }
    __syncthreads();

    float acc1 = 0.f, acc2 = 0.f;
    int u_ac = 0, c_ac = 0;

    if (tid < 144) {
        // term_ac: u fastest -> K-row LDS reads broadcast across lanes sharing c.
        u_ac = tid % 12;
        c_ac = tid / 12;                 // c1 = c_ac, c2 = c_ac + 12
        const float4* qr = &lds4[u_ac * 49];
        const float4* k1 = &lds4[(12 + c_ac) * 49];
        const float4* k2 = &lds4[(24 + c_ac) * 49];
#pragma unroll 4
        for (int dd = 0; dd < 48; ++dd) {
            const float4 a  = qr[dd];
            const float4 b1 = k1[dd];
            const float4 b2 = k2[dd];
            acc1 += a.x * b1.x + a.y * b1.y + a.z * b1.z + a.w * b1.w;
            acc2 += a.x * b2.x + a.y * b2.y + a.z * b2.z + a.w * b2.w;
        }
    } else if (tid < 222) {
        // term_bd: 78 threads x 2 consecutive dots (i = u*13 + f).
        const int p  = tid - 144;
        const int i0 = 2 * p, i1 = i0 + 1;
        const int u0 = i0 / 13, f0 = i0 - u0 * 13;
        const int u1 = i1 / 13, f1 = i1 - u1 * 13;
        const float4* q0 = &lds4[u0 * 49];
        const float4* q1 = &lds4[u1 * 49];
        const float4* p0 = &lds4[(36 + f0) * 49];
        const float4* p1 = &lds4[(36 + f1) * 49];
#pragma unroll 4
        for (int dd = 0; dd < 48; ++dd) {
            const float4 a0 = q0[dd];
            const float4 b0 = p0[dd];
            const float4 a1 = q1[dd];
            const float4 b1 = p1[dd];
            acc1 += a0.x * b0.x + a0.y * b0.y + a0.z * b0.z + a0.w * b0.w;
            acc2 += a1.x * b1.x + a1.y * b1.y + a1.z * b1.z + a1.w * b1.w;
        }
        bd_s[i0] = acc1;
        bd_s[i1] = acc2;
    }
    __syncthreads();

    if (tid < 144) {
        // Rel-shift combine: j = u*24+c; u' = j/25; f' = j%25; f'<13 ? bd : 0
        const int j1 = u_ac * 24 + c_ac;
        const int j2 = j1 + 12;
        {
            const int up = j1 / 25, fp = j1 - up * 25;
            out_s[j1] = acc1 + ((fp < F_) ? bd_s[up * 13 + fp] : 0.f);
        }
        {
            const int up = j2 / 25, fp = j2 - up * 25;
            out_s[j2] = acc2 + ((fp < F_) ? bd_s[up * 13 + fp] : 0.f);
        }
    }
    __syncthreads();

    // Coalesced contiguous store: out[b][h][w][u][c], 288 floats.
    const int b = bw / W_;
    const int w = bw - b * W_;
    float* po = out + (((size_t)b * H_ + h) * W_ + w) * UK_;
    for (int i = tid; i < UK_; i += 256) {
        po[i] = out_s[i];
    }
}

extern "C" void kernel_launch(void* const* d_in, const int* in_sizes, int n_in,
                              void* d_out, int out_size, void* d_ws, size_t ws_size,
                              hipStream_t stream) {
    const float* q  = (const float*)d_in[0];   // [B,W,U,H,D]
    const float* k  = (const float*)d_in[1];   // [B,W,K,H,D]
    const float* pw = (const float*)d_in[2];   // [CH,CH]
    float* proj = (float*)d_ws;                // [F][CH] = 79872 B scratch
    float* o    = (float*)d_out;               // [B,H,W,U,K]

    hipLaunchKernelGGL(proj_kernel, dim3(13 * 6), dim3(256), 0, stream, pw, proj);
    hipLaunchKernelGGL(main_kernel, dim3(B_ * W_ * H_), dim3(256), 0, stream,
                       q, k, proj, o);
}